// Round 14
// baseline (484.488 us; speedup 1.0000x reference)
//
#include <hip/hip_runtime.h>
#include <hip/hip_bf16.h>

// MHGCN: out = 0.5*(U1+U2), U1 = S@(feat@W1)+b1, U2 = S@(U1@W2)+b2,
// S = temp + temp^T, temp = einsum('ijk,kl->ij', A_stack, weight_b). N=8192.
//
// GEMM occupancy series: 4 blocks/CU (R8)=425 > 2/CU (R10)=434 > 1/CU
// (R11)=447 -> TLP-limited. R13: BK=64, LDS 20KB -> 8 blocks/CU (2x R8).
//
//  1) k_sym_build: A_stack -> S bf16 (GL16 dense staging, bf16 T1/T2)
//  2) k_small_gemm_t: feature@W1 -> H1t bf16 [64][N]
//  3) k_gemm_skinny<0>: U1 = S@H1 + b1   (BK=64, 8 blocks/CU)
//  4) k_small_gemm_t: U1@W2 -> H2t
//  5) k_gemm_skinny<1>: out = 0.5*(U1 + S@H2 + b2)

#define NN 8192

typedef __attribute__((ext_vector_type(8))) short short8;
typedef __attribute__((ext_vector_type(8))) unsigned short u16x8;
typedef __attribute__((ext_vector_type(4))) unsigned short u16x4;
typedef __attribute__((ext_vector_type(4))) float f32x4;

static __device__ __forceinline__ unsigned short f2bf(float f) {
    unsigned u = __float_as_uint(f);
    u += 0x7FFFu + ((u >> 16) & 1u);     // round-to-nearest-even
    return (unsigned short)(u >> 16);
}
static __device__ __forceinline__ float bf2f(unsigned short h) {
    return __uint_as_float((unsigned)h << 16);
}

#define GL16(gsrc, ldst) __builtin_amdgcn_global_load_lds( \
    (const __attribute__((address_space(1))) void*)(gsrc), \
    (__attribute__((address_space(3))) void*)(ldst), 16, 0, 0)

// ---------------------------------------------------------------------------
// 1) S = temp + temp^T (bf16). Upper-tri 64x64 tile pairs; A read exactly once
//    with dense GL16 staging (16-row batches, 20KB). T1/T2 staged bf16.
// ---------------------------------------------------------------------------
__global__ __launch_bounds__(256) void k_sym_build(
        const float* __restrict__ A, const float* __restrict__ wb,
        unsigned short* __restrict__ S) {
    __shared__ float Raw[16 * 320];           // 20 KB staging
    __shared__ unsigned short T1s[64 * 72];   // temp1 row-major, bf16
    __shared__ unsigned short T2t[64 * 72];   // temp2 transposed, bf16

    int b = blockIdx.x;
    double disc = 66049.0 - 8.0 * (double)b;
    int bi = (int)((257.0 - sqrt(disc)) * 0.5);
    if (bi < 0) bi = 0; if (bi > 127) bi = 127;
    while (bi < 127 && (bi + 1) * (257 - (bi + 1)) / 2 <= b) ++bi;
    while (bi > 0 && bi * (257 - bi) / 2 > b) --bi;
    int bj = bi + (b - bi * (257 - bi) / 2);

    const float w0 = wb[0], w1 = wb[1], w2 = wb[2], w3 = wb[3], w4 = wb[4];
    int t = threadIdx.x;

    int srow[5], srem[5];
    #pragma unroll
    for (int q = 0; q < 5; ++q) {
        int o = t * 16 + q * 4096;       // byte offset in 20480B batch
        srow[q] = o / 1280;              // row in batch (0..15)
        srem[q] = (o % 1280) >> 2;       // float offset in row
    }
    int cr = t >> 4;                     // compute: row in batch
    int cj = t & 15;                     // col base (cols cj + 16e)

    #pragma unroll
    for (int half = 0; half < 2; ++half) {
        int tr = half == 0 ? bi : bj;    // tile row-base in A
        int tc = half == 0 ? bj : bi;    // tile col-base
        for (int bat = 0; bat < 4; ++bat) {
            #pragma unroll
            for (int q = 0; q < 5; ++q) {
                const float* src = A +
                    ((long long)(tr * 64 + bat * 16 + srow[q]) * NN + tc * 64) * 5
                    + srem[q];
                GL16(src, (char*)Raw + t * 16 + q * 4096);
            }
            __syncthreads();             // staging visible
            int gr = bat * 16 + cr;
            #pragma unroll
            for (int e = 0; e < 4; ++e) {
                int j = cj + 16 * e;
                const float* p = &Raw[cr * 320 + 5 * j];
                float tv = p[0]*w0 + p[1]*w1 + p[2]*w2 + p[3]*w3 + p[4]*w4;
                if (half == 0) T1s[gr * 72 + j] = f2bf(tv);
                else           T2t[j * 72 + gr] = f2bf(tv);
            }
            __syncthreads();             // Raw reusable
        }
    }

    // Phase B: main tile  S[bi..][bj..][i][j] = T1[i][j] + T2[j][i]
    #pragma unroll
    for (int e = 0; e < 2; ++e) {
        int i = (t >> 3) + 32 * e;
        int j0 = (t & 7) * 8;
        u16x8 v1 = *(const u16x8*)&T1s[i * 72 + j0];
        u16x8 v2 = *(const u16x8*)&T2t[i * 72 + j0];
        u16x8 o;
        #pragma unroll
        for (int q = 0; q < 8; ++q)
            o[q] = f2bf(bf2f(v1[q]) + bf2f(v2[q]));
        *(u16x8*)(S + (long long)(bi * 64 + i) * NN + bj * 64 + j0) = o;
    }
    // Phase C: mirror tile S[bj..][bi..][i][j] = tile[j][i]
    if (bi != bj) {
        #pragma unroll
        for (int e = 0; e < 2; ++e) {
            int i = (t >> 3) + 32 * e;
            int j0 = (t & 7) * 8;
            u16x8 o;
            #pragma unroll
            for (int q = 0; q < 8; ++q)
                o[q] = f2bf(bf2f(T1s[(j0 + q) * 72 + i]) + bf2f(T2t[(j0 + q) * 72 + i]));
            *(u16x8*)(S + (long long)(bj * 64 + i) * NN + bi * 64 + j0) = o;
        }
    }
}

// ---------------------------------------------------------------------------
// 2/4) Yt[c][row] = sum_k X[row][k]*W[k][c]   (bf16, transposed output)
// ---------------------------------------------------------------------------
__global__ __launch_bounds__(256) void k_small_gemm_t(
        const float* __restrict__ X, const float* __restrict__ W,
        unsigned short* __restrict__ Yt) {
    __shared__ float Ys[64 * 65];
    int t = threadIdx.x, lane = t & 63, w = t >> 6;
    float wcol[64];
    #pragma unroll
    for (int k = 0; k < 64; ++k) wcol[k] = W[k * 64 + lane];
    int r0 = blockIdx.x * 64;
    for (int rr = 0; rr < 16; ++rr) {
        const f32x4* x = (const f32x4*)(X + (long long)(r0 + w * 16 + rr) * 64);
        float acc = 0.f;
        #pragma unroll
        for (int k4 = 0; k4 < 16; ++k4) {
            f32x4 xv = x[k4];
            acc += xv[0]*wcol[4*k4] + xv[1]*wcol[4*k4+1]
                 + xv[2]*wcol[4*k4+2] + xv[3]*wcol[4*k4+3];
        }
        Ys[lane * 65 + w * 16 + rr] = acc;    // Ys[col][row-in-tile]
    }
    __syncthreads();
    int c = t >> 2, j0 = (t & 3) * 16;
    u16x8 o0, o1;
    #pragma unroll
    for (int q = 0; q < 8; ++q) {
        o0[q] = f2bf(Ys[c * 65 + j0 + q]);
        o1[q] = f2bf(Ys[c * 65 + j0 + 8 + q]);
    }
    *(u16x8*)(Yt + (long long)c * NN + r0 + j0) = o0;
    *(u16x8*)(Yt + (long long)c * NN + r0 + j0 + 8) = o1;
}

// ---------------------------------------------------------------------------
// 3/5) Y[i][f] = (FINAL? 0.5*(U1+.) : .)(bias[f] + sum_j S[i][j]*H[j][f])
//   BK=64: Ts 2x2KB + Hs 2x8KB = 20KB LDS -> 8 blocks/CU (32 waves/CU).
//   global_load_lds dbuf; pre-swizzled global source, XOR ds_read (row
//   stride 128B; (row&7)<<4 spreads 16 rows over 8 slots = 2-way = free).
//   2 MFMAs/wave/iter; 128 iters; one __syncthreads per iter.
// ---------------------------------------------------------------------------
template<int FINAL>
__global__ __launch_bounds__(256) void k_gemm_skinny(
        const unsigned short* __restrict__ S,
        const unsigned short* __restrict__ Ht,   // [64][NN]
        const float* __restrict__ bias,
        const float* __restrict__ U1,
        float* __restrict__ Y) {
    __shared__ unsigned short Ts[2][16 * 64];    // 2 x 2 KB
    __shared__ unsigned short Hs[2][64 * 64];    // 2 x 8 KB
    int t = threadIdx.x, lane = t & 63, w = t >> 6;
    int i0 = blockIdx.x * 16;
    int r = lane & 15, kg = lane >> 4;

    // Ts staging (threads 0..127): chunk t -> row t>>3, 16B slot t&7
    int arow = t >> 3, ac = t & 7;
    int abyte = (ac * 16) ^ ((arow & 7) << 4);
    const unsigned short* aSrc = S + (long long)(i0 + arow) * NN + (abyte >> 1);
    // Hs staging (all threads, 2 chunks): e0 = t, e1 = t + 256
    int h0r = t >> 3, h0c = t & 7;
    int h1r = h0r + 32;
    int h0b = (h0c * 16) ^ ((h0r & 7) << 4);
    int h1b = (h0c * 16) ^ ((h1r & 7) << 4);
    const unsigned short* hSrc0 = Ht + (long long)h0r * NN + (h0b >> 1);
    const unsigned short* hSrc1 = Ht + (long long)h1r * NN + (h1b >> 1);

    f32x4 acc = {0.f, 0.f, 0.f, 0.f};
    int hr = w * 16 + r;

    auto stage = [&](int tile, int d) {
        if (t < 128) GL16(aSrc + tile * 64, (char*)&Ts[d][0] + t * 16);
        GL16(hSrc0 + tile * 64, (char*)&Hs[d][0] + t * 16);
        GL16(hSrc1 + tile * 64, (char*)&Hs[d][0] + 4096 + t * 16);
    };
    auto compute = [&](int d) {
        const char* tsB = (const char*)&Ts[d][0];
        const char* hsB = (const char*)&Hs[d][0];
        #pragma unroll
        for (int kk = 0; kk < 2; ++kk) {
            int xo = kk * 64 + kg * 16;
            short8 a = *(const short8*)(tsB + r * 128 + (xo ^ ((r & 7) << 4)));
            short8 bb = *(const short8*)(hsB + hr * 128 + (xo ^ ((r & 7) << 4)));
            acc = __builtin_amdgcn_mfma_f32_16x16x32_bf16(a, bb, acc, 0, 0, 0);
        }
    };

    stage(0, 0);
    __syncthreads();
    int cur = 0;
    for (int k = 0; k < 128; ++k) {
        if (k + 1 < 128) stage(k + 1, cur ^ 1);
        compute(cur);
        __syncthreads();                 // drains vmcnt (next buf ready) + lgkm
        cur ^= 1;
    }

    int f = w * 16 + r;
    float bv = bias[f];
    #pragma unroll
    for (int rr = 0; rr < 4; ++rr) {
        long long gi = (long long)(i0 + kg * 4 + rr) * 64 + f;
        float v = acc[rr] + bv;
        if (FINAL) v = 0.5f * (U1[gi] + v);
        Y[gi] = v;
    }
}

// ---------------------------------------------------------------------------
extern "C" void kernel_launch(void* const* d_in, const int* in_sizes, int n_in,
                              void* d_out, int out_size, void* d_ws, size_t ws_size,
                              hipStream_t stream) {
    const float* A    = (const float*)d_in[0];
    const float* feat = (const float*)d_in[1];
    const float* wb   = (const float*)d_in[2];
    const float* W1   = (const float*)d_in[3];
    const float* b1   = (const float*)d_in[4];
    const float* W2   = (const float*)d_in[5];
    const float* b2   = (const float*)d_in[6];
    float* out = (float*)d_out;

    const size_t szS = (size_t)NN * NN * 2;       // 128 MB bf16 S
    const size_t szH = (size_t)64 * NN * 2;       // 1 MB  bf16 Ht
    char* p = (char*)d_ws;
    unsigned short* S   = (unsigned short*)p;
    unsigned short* H1t = (unsigned short*)(p + szS);
    unsigned short* H2t = (unsigned short*)(p + szS + szH);
    float*          U1  = (float*)(p + szS + 2 * szH);

    k_sym_build<<<8256, 256, 0, stream>>>(A, wb, S);
    k_small_gemm_t<<<128, 256, 0, stream>>>(feat, W1, H1t);
    k_gemm_skinny<0><<<512, 256, 0, stream>>>(S, H1t, b1, nullptr, U1);
    k_small_gemm_t<<<128, 256, 0, stream>>>(U1, W2, H2t);
    k_gemm_skinny<1><<<512, 256, 0, stream>>>(S, H2t, b2, U1, out);
}

// Round 15
// 425.695 us; speedup vs baseline: 1.1381x; 1.1381x over previous
//
#include <hip/hip_runtime.h>
#include <hip/hip_bf16.h>

// MHGCN: out = 0.5*(U1+U2), U1 = S@(feat@W1)+b1, U2 = S@(U1@W2)+b2,
// S = temp + temp^T, temp = einsum('ijk,kl->ij', A_stack, weight_b). N=8192.
//
// GEMM series: 8/CU(BK64)=484, 4/CU(R8 drain)=425, 2/CU(ring)=434, 1/CU=447.
// R14: drain-free depth-2 counted-vmcnt pipeline AT 4 blocks/CU (40KB) —
// isolates drain-removal from occupancy for the first time.
//
//  1) k_sym_build: A_stack -> S bf16 (GL16 dense staging, bf16 T1/T2, 4/CU)
//  2) k_small_gemm_t: feature@W1 -> H1t bf16 [64][N]
//  3) k_gemm_skinny<0>: U1 = S@H1 + b1   (depth-2 counted vmcnt, 2 barriers/iter)
//  4) k_small_gemm_t: U1@W2 -> H2t
//  5) k_gemm_skinny<1>: out = 0.5*(U1 + S@H2 + b2)

#define NN 8192

typedef __attribute__((ext_vector_type(8))) short short8;
typedef __attribute__((ext_vector_type(8))) unsigned short u16x8;
typedef __attribute__((ext_vector_type(4))) unsigned short u16x4;
typedef __attribute__((ext_vector_type(4))) float f32x4;

static __device__ __forceinline__ unsigned short f2bf(float f) {
    unsigned u = __float_as_uint(f);
    u += 0x7FFFu + ((u >> 16) & 1u);     // round-to-nearest-even
    return (unsigned short)(u >> 16);
}
static __device__ __forceinline__ float bf2f(unsigned short h) {
    return __uint_as_float((unsigned)h << 16);
}

#define GL16(gsrc, ldst) __builtin_amdgcn_global_load_lds( \
    (const __attribute__((address_space(1))) void*)(gsrc), \
    (__attribute__((address_space(3))) void*)(ldst), 16, 0, 0)

// ---------------------------------------------------------------------------
// 1) S = temp + temp^T (bf16). Upper-tri 64x64 tile pairs; A read exactly once
//    with dense GL16 staging (16-row batches, 20KB). T1/T2 staged bf16 ->
//    38.9KB LDS -> 4 blocks/CU.
// ---------------------------------------------------------------------------
__global__ __launch_bounds__(256) void k_sym_build(
        const float* __restrict__ A, const float* __restrict__ wb,
        unsigned short* __restrict__ S) {
    __shared__ float Raw[16 * 320];           // 20 KB staging
    __shared__ unsigned short T1s[64 * 72];   // temp1 row-major, bf16
    __shared__ unsigned short T2t[64 * 72];   // temp2 transposed, bf16

    int b = blockIdx.x;
    double disc = 66049.0 - 8.0 * (double)b;
    int bi = (int)((257.0 - sqrt(disc)) * 0.5);
    if (bi < 0) bi = 0; if (bi > 127) bi = 127;
    while (bi < 127 && (bi + 1) * (257 - (bi + 1)) / 2 <= b) ++bi;
    while (bi > 0 && bi * (257 - bi) / 2 > b) --bi;
    int bj = bi + (b - bi * (257 - bi) / 2);

    const float w0 = wb[0], w1 = wb[1], w2 = wb[2], w3 = wb[3], w4 = wb[4];
    int t = threadIdx.x;

    int srow[5], srem[5];
    #pragma unroll
    for (int q = 0; q < 5; ++q) {
        int o = t * 16 + q * 4096;       // byte offset in 20480B batch
        srow[q] = o / 1280;              // row in batch (0..15)
        srem[q] = (o % 1280) >> 2;       // float offset in row
    }
    int cr = t >> 4;                     // compute: row in batch
    int cj = t & 15;                     // col base (cols cj + 16e)

    #pragma unroll
    for (int half = 0; half < 2; ++half) {
        int tr = half == 0 ? bi : bj;    // tile row-base in A
        int tc = half == 0 ? bj : bi;    // tile col-base
        for (int bat = 0; bat < 4; ++bat) {
            #pragma unroll
            for (int q = 0; q < 5; ++q) {
                const float* src = A +
                    ((long long)(tr * 64 + bat * 16 + srow[q]) * NN + tc * 64) * 5
                    + srem[q];
                GL16(src, (char*)Raw + t * 16 + q * 4096);
            }
            __syncthreads();             // staging visible
            int gr = bat * 16 + cr;
            #pragma unroll
            for (int e = 0; e < 4; ++e) {
                int j = cj + 16 * e;
                const float* p = &Raw[cr * 320 + 5 * j];
                float tv = p[0]*w0 + p[1]*w1 + p[2]*w2 + p[3]*w3 + p[4]*w4;
                if (half == 0) T1s[gr * 72 + j] = f2bf(tv);
                else           T2t[j * 72 + gr] = f2bf(tv);
            }
            __syncthreads();             // Raw reusable
        }
    }

    // Phase B: main tile  S[bi..][bj..][i][j] = T1[i][j] + T2[j][i]
    #pragma unroll
    for (int e = 0; e < 2; ++e) {
        int i = (t >> 3) + 32 * e;
        int j0 = (t & 7) * 8;
        u16x8 v1 = *(const u16x8*)&T1s[i * 72 + j0];
        u16x8 v2 = *(const u16x8*)&T2t[i * 72 + j0];
        u16x8 o;
        #pragma unroll
        for (int q = 0; q < 8; ++q)
            o[q] = f2bf(bf2f(v1[q]) + bf2f(v2[q]));
        *(u16x8*)(S + (long long)(bi * 64 + i) * NN + bj * 64 + j0) = o;
    }
    // Phase C: mirror tile S[bj..][bi..][i][j] = tile[j][i]
    if (bi != bj) {
        #pragma unroll
        for (int e = 0; e < 2; ++e) {
            int i = (t >> 3) + 32 * e;
            int j0 = (t & 7) * 8;
            u16x8 o;
            #pragma unroll
            for (int q = 0; q < 8; ++q)
                o[q] = f2bf(bf2f(T1s[(j0 + q) * 72 + i]) + bf2f(T2t[(j0 + q) * 72 + i]));
            *(u16x8*)(S + (long long)(bj * 64 + i) * NN + bi * 64 + j0) = o;
        }
    }
}

// ---------------------------------------------------------------------------
// 2/4) Yt[c][row] = sum_k X[row][k]*W[k][c]   (bf16, transposed output)
// ---------------------------------------------------------------------------
__global__ __launch_bounds__(256) void k_small_gemm_t(
        const float* __restrict__ X, const float* __restrict__ W,
        unsigned short* __restrict__ Yt) {
    __shared__ float Ys[64 * 65];
    int t = threadIdx.x, lane = t & 63, w = t >> 6;
    float wcol[64];
    #pragma unroll
    for (int k = 0; k < 64; ++k) wcol[k] = W[k * 64 + lane];
    int r0 = blockIdx.x * 64;
    for (int rr = 0; rr < 16; ++rr) {
        const f32x4* x = (const f32x4*)(X + (long long)(r0 + w * 16 + rr) * 64);
        float acc = 0.f;
        #pragma unroll
        for (int k4 = 0; k4 < 16; ++k4) {
            f32x4 xv = x[k4];
            acc += xv[0]*wcol[4*k4] + xv[1]*wcol[4*k4+1]
                 + xv[2]*wcol[4*k4+2] + xv[3]*wcol[4*k4+3];
        }
        Ys[lane * 65 + w * 16 + rr] = acc;    // Ys[col][row-in-tile]
    }
    __syncthreads();
    int c = t >> 2, j0 = (t & 3) * 16;
    u16x8 o0, o1;
    #pragma unroll
    for (int q = 0; q < 8; ++q) {
        o0[q] = f2bf(Ys[c * 65 + j0 + q]);
        o1[q] = f2bf(Ys[c * 65 + j0 + 8 + q]);
    }
    *(u16x8*)(Yt + (long long)c * NN + r0 + j0) = o0;
    *(u16x8*)(Yt + (long long)c * NN + r0 + j0 + 8) = o1;
}

// ---------------------------------------------------------------------------
// 3/5) Y[i][f] = (FINAL? 0.5*(U1+.) : .)(bias[f] + sum_j S[i][j]*H[j][f])
//   Depth-2 counted-vmcnt pipeline at 4 blocks/CU (40KB LDS, BK=128).
//   Per iter: stage(k+1,buf^1) -> vmcnt(5) [tile k landed, k+1 flying] ->
//   s_barrier -> compute(k) -> s_barrier. No full drain in steady state.
// ---------------------------------------------------------------------------
template<int FINAL>
__global__ __launch_bounds__(256) void k_gemm_skinny(
        const unsigned short* __restrict__ S,
        const unsigned short* __restrict__ Ht,   // [64][NN]
        const float* __restrict__ bias,
        const float* __restrict__ U1,
        float* __restrict__ Y) {
    __shared__ unsigned short Ts[2][16 * 128];   // 2 x 4 KB
    __shared__ unsigned short Hs[2][64 * 128];   // 2 x 16 KB
    int t = threadIdx.x, lane = t & 63, w = t >> 6;
    int i0 = blockIdx.x * 16;
    int r = lane & 15, kg = lane >> 4;

    int srow = t >> 4, sc = t & 15;
    int sbyte = (sc * 16) ^ ((srow & 7) << 4);   // pre-swizzled source col
    const unsigned short* aSrc = S + (long long)(i0 + srow) * NN + (sbyte >> 1);
    const unsigned short* hSrc = Ht + (long long)srow * NN + (sbyte >> 1);

    f32x4 acc = {0.f, 0.f, 0.f, 0.f};
    int hr = w * 16 + r;

    auto stage = [&](int jt, int d) {            // 5 GL16 / thread
        GL16(aSrc + jt, (char*)&Ts[d][0] + t * 16);
        #pragma unroll
        for (int q = 0; q < 4; ++q)
            GL16(hSrc + (long long)q * 16 * NN + jt, (char*)&Hs[d][0] + t * 16 + q * 4096);
    };
    auto compute = [&](int d) {
        const char* tsB = (const char*)&Ts[d][0];
        const char* hsB = (const char*)&Hs[d][0];
        #pragma unroll
        for (int kk = 0; kk < 4; ++kk) {
            int xo = kk * 64 + kg * 16;
            short8 a = *(const short8*)(tsB + r * 256 + (xo ^ ((r & 7) << 4)));
            short8 bb = *(const short8*)(hsB + hr * 256 + (xo ^ ((r & 7) << 4)));
            acc = __builtin_amdgcn_mfma_f32_16x16x32_bf16(a, bb, acc, 0, 0, 0);
        }
    };

    stage(0, 0);                                 // prologue: 5 outstanding
    int cur = 0;
    for (int k = 0; k < 63; ++k) {
        stage((k + 1) * 128, cur ^ 1);           // buf^1 free: readers done at
                                                 // prev iter's 2nd barrier
        asm volatile("s_waitcnt vmcnt(5)" ::: "memory");  // tile k landed (own)
        __builtin_amdgcn_s_barrier();            // all waves: tile k staged
        __builtin_amdgcn_sched_barrier(0);
        compute(cur);
        __builtin_amdgcn_s_barrier();            // all waves done reading cur
        __builtin_amdgcn_sched_barrier(0);
        cur ^= 1;
    }
    asm volatile("s_waitcnt vmcnt(0)" ::: "memory");     // last tile landed
    __builtin_amdgcn_s_barrier();
    __builtin_amdgcn_sched_barrier(0);
    compute(cur);

    int f = w * 16 + r;
    float bv = bias[f];
    #pragma unroll
    for (int rr = 0; rr < 4; ++rr) {
        long long gi = (long long)(i0 + kg * 4 + rr) * 64 + f;
        float v = acc[rr] + bv;
        if (FINAL) v = 0.5f * (U1[gi] + v);
        Y[gi] = v;
    }
}

// ---------------------------------------------------------------------------
extern "C" void kernel_launch(void* const* d_in, const int* in_sizes, int n_in,
                              void* d_out, int out_size, void* d_ws, size_t ws_size,
                              hipStream_t stream) {
    const float* A    = (const float*)d_in[0];
    const float* feat = (const float*)d_in[1];
    const float* wb   = (const float*)d_in[2];
    const float* W1   = (const float*)d_in[3];
    const float* b1   = (const float*)d_in[4];
    const float* W2   = (const float*)d_in[5];
    const float* b2   = (const float*)d_in[6];
    float* out = (float*)d_out;

    const size_t szS = (size_t)NN * NN * 2;       // 128 MB bf16 S
    const size_t szH = (size_t)64 * NN * 2;       // 1 MB  bf16 Ht
    char* p = (char*)d_ws;
    unsigned short* S   = (unsigned short*)p;
    unsigned short* H1t = (unsigned short*)(p + szS);
    unsigned short* H2t = (unsigned short*)(p + szS + szH);
    float*          U1  = (float*)(p + szS + 2 * szH);

    k_sym_build<<<8256, 256, 0, stream>>>(A, wb, S);
    k_small_gemm_t<<<128, 256, 0, stream>>>(feat, W1, H1t);
    k_gemm_skinny<0><<<512, 256, 0, stream>>>(S, H1t, b1, nullptr, U1);
    k_small_gemm_t<<<128, 256, 0, stream>>>(U1, W2, H2t);
    k_gemm_skinny<1><<<512, 256, 0, stream>>>(S, H2t, b2, U1, out);
}